// Round 1
// baseline (513.936 us; speedup 1.0000x reference)
//
#include <hip/hip_runtime.h>

typedef __attribute__((ext_vector_type(8))) short short8;
typedef __attribute__((ext_vector_type(4))) float floatx4;

#define B_  64
#define N_  4096
#define DIN 192
#define S_  11
#define E_  128

__device__ inline unsigned short f2bf(float f) {
    union { float f; unsigned u; } v; v.f = f;
    unsigned r = v.u + 0x7FFF + ((v.u >> 16) & 1);
    return (unsigned short)(r >> 16);
}
__device__ inline floatx4 fzero4() { floatx4 v; v[0]=v[1]=v[2]=v[3]=0.f; return v; }

// ---------------------------------------------------------------- K0: weight prep
// Wkv_bf[o][j] = (o<128?Wk:Wv)[o][j] * ln_in_g[j]  (bf16), bias_kv[o] = sum_j ln_in_b[j]*W[o][j]
// Wq_s[e][j]   = Wq[e][j] * ln_s_g[j] * scale,      bias_q[e]  = scale * sum_j ln_s_b[j]*Wq[e][j]
__global__ void k0_prep(const float* __restrict__ Wk, const float* __restrict__ Wv,
                        const float* __restrict__ ln_in_g, const float* __restrict__ ln_in_b,
                        const float* __restrict__ Wq, const float* __restrict__ ln_s_g,
                        const float* __restrict__ ln_s_b,
                        unsigned short* __restrict__ Wkv_bf, float* __restrict__ bias_kv,
                        float* __restrict__ Wq_s, float* __restrict__ bias_q) {
    int o = blockIdx.x, t = threadIdx.x;
    if (o < 256) {
        const float* src = (o < 128) ? (Wk + (size_t)o * DIN) : (Wv + (size_t)(o - 128) * DIN);
        float bs = 0.f;
        for (int j = t; j < DIN; j += 64) {
            float w = src[j];
            Wkv_bf[(size_t)o * DIN + j] = f2bf(w * ln_in_g[j]);
            bs += w * ln_in_b[j];
        }
        #pragma unroll
        for (int off = 32; off > 0; off >>= 1) bs += __shfl_down(bs, off);
        if (t == 0) bias_kv[o] = bs;
    } else {
        int e = o - 256;
        const float sc = 0.08838834764831845f;  // 1/sqrt(128)
        float bs = 0.f;
        for (int j = t; j < E_; j += 64) {
            float w = Wq[(size_t)e * E_ + j];
            Wq_s[(size_t)e * E_ + j] = w * ln_s_g[j] * sc;
            bs += w * ln_s_b[j];
        }
        #pragma unroll
        for (int off = 32; off > 0; off >>= 1) bs += __shfl_down(bs, off);
        if (t == 0) bias_q[e] = bs * sc;
    }
}

// ---------------------------------------------------------------- K1: LN + K/V projection (MFMA)
#define WPAD 200
#define APAD 200
#define VPAD 72
__global__ __launch_bounds__(256)
void k1_lnproj(const float* __restrict__ inp, const unsigned short* __restrict__ Wkv,
               const float* __restrict__ bias_kv,
               unsigned short* __restrict__ k1o, unsigned short* __restrict__ v1T) {
    __shared__ unsigned short Wl[256 * WPAD];   // 102400 B
    __shared__ unsigned short Al[64 * APAD];    //  25600 B (reused as V transpose buf)
    int t = threadIdx.x, lane = t & 63, wid = t >> 6;
    long rowbase = (long)blockIdx.x * 64;
    int bb = (int)(rowbase >> 12);
    int nbase = (int)(rowbase & 4095);

    { // stage W: thread t -> weight row t (192 bf16 = 24 x short8)
        const short8* src = (const short8*)(Wkv + (size_t)t * DIN);
        short8* dst = (short8*)(Wl + (size_t)t * WPAD);
        #pragma unroll
        for (int j = 0; j < 24; ++j) dst[j] = src[j];
    }
    { // stage A with LN: thread t -> row (t>>2), quarter (t&3); LN over 192 via quad shuffles
        int r = t >> 2, q = t & 3;
        const floatx4* src = (const floatx4*)(inp + (rowbase + r) * DIN + q * 48);
        floatx4 v[12];
        float s1 = 0.f, s2 = 0.f;
        #pragma unroll
        for (int j = 0; j < 12; ++j) {
            v[j] = src[j];
            #pragma unroll
            for (int e = 0; e < 4; ++e) { s1 += v[j][e]; s2 += v[j][e] * v[j][e]; }
        }
        s1 += __shfl_xor(s1, 1); s1 += __shfl_xor(s1, 2);
        s2 += __shfl_xor(s2, 1); s2 += __shfl_xor(s2, 2);
        float mean = s1 * (1.f / 192.f);
        float var = s2 * (1.f / 192.f) - mean * mean;
        float rs = rsqrtf(var + 1e-5f);
        short8* dst = (short8*)(Al + (size_t)r * APAD + q * 48);
        #pragma unroll
        for (int j = 0; j < 6; ++j) {
            short8 w;
            #pragma unroll
            for (int e = 0; e < 4; ++e) {
                w[e]     = (short)f2bf((v[2 * j][e]     - mean) * rs);
                w[4 + e] = (short)f2bf((v[2 * j + 1][e] - mean) * rs);
            }
            dst[j] = w;
        }
    }
    __syncthreads();

    int c = lane & 15, g = lane >> 4;
    floatx4 acc[16];
    #pragma unroll
    for (int i = 0; i < 16; ++i) acc[i] = fzero4();
    #pragma unroll
    for (int kk = 0; kk < 6; ++kk) {
        short8 a = *(const short8*)(Al + (size_t)(wid * 16 + c) * APAD + kk * 32 + g * 8);
        #pragma unroll
        for (int nt = 0; nt < 16; ++nt) {
            short8 bf = *(const short8*)(Wl + (size_t)(nt * 16 + c) * WPAD + kk * 32 + g * 8);
            acc[nt] = __builtin_amdgcn_mfma_f32_16x16x32_bf16(a, bf, acc[nt], 0, 0, 0);
        }
    }
    // k outputs: tiles 0..7  (row-major bf16 [B*N][128])
    #pragma unroll
    for (int nt = 0; nt < 8; ++nt) {
        int col = nt * 16 + c;
        float bia = bias_kv[col];
        #pragma unroll
        for (int r = 0; r < 4; ++r) {
            long row = rowbase + wid * 16 + g * 4 + r;
            k1o[row * 128 + col] = f2bf(acc[8 + nt - 8][r] + 0.f), // placeholder avoided below
            k1o[row * 128 + col] = f2bf(acc[nt][r] + bia);
        }
    }
    __syncthreads();
    // v outputs -> LDS transpose buffer Vl[d][n_local]
    unsigned short* Vl = Al;
    #pragma unroll
    for (int nt = 8; nt < 16; ++nt) {
        int d = (nt - 8) * 16 + c;
        float bia = bias_kv[128 + d];
        #pragma unroll
        for (int r = 0; r < 4; ++r) {
            int nl = wid * 16 + g * 4 + r;
            Vl[(size_t)d * VPAD + nl] = f2bf(acc[nt][r] + bia);
        }
    }
    __syncthreads();
    { // write v1T[b][d][n]: thread t -> d = t>>1, half = t&1 (32 n each)
        int d = t >> 1, hf = t & 1;
        const short8* src = (const short8*)(Vl + (size_t)d * VPAD + hf * 32);
        short8 x0 = src[0], x1 = src[1], x2 = src[2], x3 = src[3];
        short8* dst = (short8*)(v1T + (((size_t)bb * 128 + d) << 12) + nbase + hf * 32);
        dst[0] = x0; dst[1] = x1; dst[2] = x2; dst[3] = x3;
    }
}

// ---------------------------------------------------------------- K2: slot init (LN + optional MHA + MLP)
__global__ __launch_bounds__(256)
void k2_init(const float* __restrict__ islots, const int* __restrict__ ip,
             const float* __restrict__ ln_s_g, const float* __restrict__ ln_s_b,
             const float* __restrict__ in_w, const float* __restrict__ in_b,
             const float* __restrict__ out_w, const float* __restrict__ out_b,
             const float* __restrict__ w1, const float* __restrict__ b1,
             const float* __restrict__ w2, const float* __restrict__ b2,
             float* __restrict__ slotsA) {
    __shared__ float sl[11][128];
    __shared__ float qkv[11][384];
    __shared__ float att[4][11][12];
    __shared__ float oh[11][128];
    __shared__ float s2l[11][128];
    __shared__ float s3[11][128];
    __shared__ float h1[11][256];
    int t = threadIdx.x, lane = t & 63, wid = t >> 6;
    int bb = blockIdx.x;

    for (int s = wid; s < 11; s += 4) {
        const float* row = islots + ((size_t)bb * 11 + s) * 128;
        float x0 = row[lane], x1 = row[lane + 64];
        float s1 = x0 + x1, sq = x0 * x0 + x1 * x1;
        #pragma unroll
        for (int off = 32; off > 0; off >>= 1) { s1 += __shfl_xor(s1, off); sq += __shfl_xor(sq, off); }
        float mean = s1 * (1.f / 128.f), var = sq * (1.f / 128.f) - mean * mean;
        float rs = rsqrtf(var + 1e-5f);
        sl[s][lane]      = (x0 - mean) * rs * ln_s_g[lane]      + ln_s_b[lane];
        sl[s][lane + 64] = (x1 - mean) * rs * ln_s_g[lane + 64] + ln_s_b[lane + 64];
    }
    __syncthreads();
    int ival = *ip;
    if (ival != 1) {
        for (int o = t; o < 11 * 384; o += 256) {
            int s = o / 384, e = o % 384;
            const floatx4* w = (const floatx4*)(in_w + (size_t)e * 128);
            const floatx4* x = (const floatx4*)sl[s];
            float a = 0.f;
            for (int j = 0; j < 32; ++j) {
                floatx4 wv = w[j], xv = x[j];
                a += wv[0]*xv[0] + wv[1]*xv[1] + wv[2]*xv[2] + wv[3]*xv[3];
            }
            qkv[s][e] = a + in_b[e];
        }
        __syncthreads();
        for (int o = t; o < 4 * 11 * 11; o += 256) {
            int h = o / 121, ij = o % 121, i = ij / 11, j = ij % 11;
            const float* qr = &qkv[i][h * 32];
            const float* kr = &qkv[j][128 + h * 32];
            float a = 0.f;
            #pragma unroll
            for (int d = 0; d < 32; ++d) a += qr[d] * kr[d];
            att[h][i][j] = a * 0.17677669529663687f;
        }
        __syncthreads();
        if (t < 44) {
            int h = t / 11, i = t % 11;
            float mx = -1e30f;
            #pragma unroll
            for (int j = 0; j < 11; ++j) mx = fmaxf(mx, att[h][i][j]);
            float sum = 0.f, e_[11];
            #pragma unroll
            for (int j = 0; j < 11; ++j) { e_[j] = __expf(att[h][i][j] - mx); sum += e_[j]; }
            float inv = 1.f / sum;
            #pragma unroll
            for (int j = 0; j < 11; ++j) att[h][i][j] = e_[j] * inv;
        }
        __syncthreads();
        for (int o = t; o < 11 * 128; o += 256) {
            int s = o >> 7, e = o & 127, h = e >> 5;
            float a = 0.f;
            #pragma unroll
            for (int j = 0; j < 11; ++j) a += att[h][s][j] * qkv[j][256 + e];
            oh[s][e] = a;
        }
        __syncthreads();
        for (int o = t; o < 11 * 128; o += 256) {
            int s = o >> 7, e = o & 127;
            const floatx4* w = (const floatx4*)(out_w + (size_t)e * 128);
            const floatx4* x = (const floatx4*)oh[s];
            float a = 0.f;
            for (int j = 0; j < 32; ++j) {
                floatx4 wv = w[j], xv = x[j];
                a += wv[0]*xv[0] + wv[1]*xv[1] + wv[2]*xv[2] + wv[3]*xv[3];
            }
            s2l[s][e] = sl[s][e] + a + out_b[e];
        }
        __syncthreads();
        for (int s = wid; s < 11; s += 4) {
            float x0 = s2l[s][lane], x1 = s2l[s][lane + 64];
            float s1 = x0 + x1, sq = x0 * x0 + x1 * x1;
            #pragma unroll
            for (int off = 32; off > 0; off >>= 1) { s1 += __shfl_xor(s1, off); sq += __shfl_xor(sq, off); }
            float mean = s1 * (1.f / 128.f), var = sq * (1.f / 128.f) - mean * mean;
            float rs = rsqrtf(var + 1e-5f);
            s3[s][lane]      = (x0 - mean) * rs * ln_s_g[lane]      + ln_s_b[lane];
            s3[s][lane + 64] = (x1 - mean) * rs * ln_s_g[lane + 64] + ln_s_b[lane + 64];
        }
        __syncthreads();
        for (int o = t; o < 11 * 256; o += 256) {
            int s = o >> 8, k = o & 255;
            const floatx4* w = (const floatx4*)(w1 + (size_t)k * 128);
            const floatx4* x = (const floatx4*)s3[s];
            float a = 0.f;
            for (int j = 0; j < 32; ++j) {
                floatx4 wv = w[j], xv = x[j];
                a += wv[0]*xv[0] + wv[1]*xv[1] + wv[2]*xv[2] + wv[3]*xv[3];
            }
            a += b1[k];
            h1[s][k] = a > 0.f ? a : 0.f;
        }
        __syncthreads();
        for (int o = t; o < 11 * 128; o += 256) {
            int s = o >> 7, e = o & 127;
            const floatx4* w = (const floatx4*)(w2 + (size_t)e * 256);
            const floatx4* x = (const floatx4*)h1[s];
            float a = 0.f;
            for (int j = 0; j < 64; ++j) {
                floatx4 wv = w[j], xv = x[j];
                a += wv[0]*xv[0] + wv[1]*xv[1] + wv[2]*xv[2] + wv[3]*xv[3];
            }
            slotsA[((size_t)bb * 11 + s) * 128 + e] = s3[s][e] + a + b2[e];
        }
    } else {
        for (int o = t; o < 11 * 128; o += 256) {
            int s = o >> 7, e = o & 127;
            slotsA[((size_t)bb * 11 + s) * 128 + e] = sl[s][e];
        }
    }
}

// ---------------------------------------------------------------- K3: q = LN(slots) @ Wq' + bias_q  (ln_s + scale folded)
__global__ __launch_bounds__(128)
void k3_q(const float* __restrict__ slots, const float* __restrict__ Wq_s,
          const float* __restrict__ bias_q, float* __restrict__ qbuf) {
    __shared__ float sn[128];
    __shared__ float red[4];
    int t = threadIdx.x;
    int bs = blockIdx.x;
    float x = slots[(size_t)bs * 128 + t];
    float s1 = x, s2 = x * x;
    #pragma unroll
    for (int off = 32; off > 0; off >>= 1) { s1 += __shfl_xor(s1, off); s2 += __shfl_xor(s2, off); }
    if ((t & 63) == 0) { red[(t >> 6) * 2] = s1; red[(t >> 6) * 2 + 1] = s2; }
    __syncthreads();
    float tot1 = red[0] + red[2], tot2 = red[1] + red[3];
    float mean = tot1 * (1.f / 128.f), var = tot2 * (1.f / 128.f) - mean * mean;
    float rs = rsqrtf(var + 1e-5f);
    sn[t] = (x - mean) * rs;
    __syncthreads();
    const floatx4* w = (const floatx4*)(Wq_s + (size_t)t * 128);
    const floatx4* sp = (const floatx4*)sn;
    float a = 0.f;
    for (int j = 0; j < 32; ++j) {
        floatx4 wv = w[j], sv = sp[j];
        a += wv[0]*sv[0] + wv[1]*sv[1] + wv[2]*sv[2] + wv[3]*sv[3];
    }
    qbuf[(size_t)bs * 128 + t] = a + bias_q[t];
}

// ---------------------------------------------------------------- K4: slot attention main (MFMA logits + softmax + MFMA update)
#define LGP 17
#define PPAD 72
__global__ __launch_bounds__(256)
void k4_attn(const unsigned short* __restrict__ k1, const unsigned short* __restrict__ v1T,
             const float* __restrict__ qbuf, float* __restrict__ Upart, float* __restrict__ Spart) {
    __shared__ float Lg[4][64][LGP];
    __shared__ unsigned short Pl[4][16][PPAD];
    __shared__ float Ul[4][16][132];
    int t = threadIdx.x, lane = t & 63, wid = t >> 6;
    int bb = blockIdx.x >> 4;
    int part = blockIdx.x & 15;
    int n0 = part * 256 + wid * 64;
    int c = lane & 15, g = lane >> 4;

    short8 bq[4];
    #pragma unroll
    for (int kk = 0; kk < 4; ++kk) {
        short8 f;
        if (c < 11) {
            const floatx4* qp = (const floatx4*)(qbuf + ((size_t)bb * 11 + c) * 128 + kk * 32 + g * 8);
            floatx4 q0 = qp[0], q1 = qp[1];
            #pragma unroll
            for (int e = 0; e < 4; ++e) { f[e] = (short)f2bf(q0[e]); f[4 + e] = (short)f2bf(q1[e]); }
        } else {
            #pragma unroll
            for (int e = 0; e < 8; ++e) f[e] = 0;
        }
        bq[kk] = f;
    }

    floatx4 lac[4];
    #pragma unroll
    for (int t4 = 0; t4 < 4; ++t4) {
        lac[t4] = fzero4();
        #pragma unroll
        for (int kk = 0; kk < 4; ++kk) {
            const short8* ap = (const short8*)(k1 + ((size_t)bb * 4096 + n0 + t4 * 16 + c) * 128 + kk * 32 + g * 8);
            lac[t4] = __builtin_amdgcn_mfma_f32_16x16x32_bf16(*ap, bq[kk], lac[t4], 0, 0, 0);
        }
    }
    #pragma unroll
    for (int t4 = 0; t4 < 4; ++t4)
        #pragma unroll
        for (int r = 0; r < 4; ++r)
            Lg[wid][t4 * 16 + g * 4 + r][c] = lac[t4][r];

    // per-lane softmax over 11 slots (row = lane), p = softmax + eps
    float p[11];
    {
        float mx = -1e30f;
        #pragma unroll
        for (int s = 0; s < 11; ++s) { p[s] = Lg[wid][lane][s]; mx = fmaxf(mx, p[s]); }
        float sum = 0.f;
        #pragma unroll
        for (int s = 0; s < 11; ++s) { p[s] = __expf(p[s] - mx); sum += p[s]; }
        float inv = 1.f / sum;
        #pragma unroll
        for (int s = 0; s < 11; ++s) p[s] = p[s] * inv + 1e-8f;
    }
    #pragma unroll
    for (int s = 0; s < 11; ++s) Pl[wid][s][lane] = f2bf(p[s]);

    floatx4 uac[8];
    floatx4 sac = fzero4();
    #pragma unroll
    for (int dt = 0; dt < 8; ++dt) uac[dt] = fzero4();
    short8 ones;
    #pragma unroll
    for (int e = 0; e < 8; ++e) ones[e] = (short)0x3F80;
    #pragma unroll
    for (int kk = 0; kk < 2; ++kk) {
        short8 ap = *(const short8*)(&Pl[wid][c][kk * 32 + g * 8]);
        #pragma unroll
        for (int dt = 0; dt < 8; ++dt) {
            const short8* vp = (const short8*)(v1T + ((size_t)bb * 128 + dt * 16 + c) * 4096 + n0 + kk * 32 + g * 8);
            uac[dt] = __builtin_amdgcn_mfma_f32_16x16x32_bf16(ap, *vp, uac[dt], 0, 0, 0);
        }
        sac = __builtin_amdgcn_mfma_f32_16x16x32_bf16(ap, ones, sac, 0, 0, 0);
    }
    #pragma unroll
    for (int dt = 0; dt < 8; ++dt)
        #pragma unroll
        for (int r = 0; r < 4; ++r)
            Ul[wid][g * 4 + r][dt * 16 + c] = uac[dt][r];
    if (c == 0) {
        #pragma unroll
        for (int r = 0; r < 4; ++r) Ul[wid][g * 4 + r][128] = sac[r];
    }
    __syncthreads();
    for (int idx = t; idx < 11 * 129; idx += 256) {
        int s = idx / 129, cc = idx % 129;
        float v = Ul[0][s][cc] + Ul[1][s][cc] + Ul[2][s][cc] + Ul[3][s][cc];
        if (cc < 128) Upart[(((size_t)bb * 16 + part) * 11 + s) * 128 + cc] = v;
        else          Spart[((size_t)bb * 16 + part) * 11 + s] = v;
    }
}

// ---------------------------------------------------------------- K5: reduce partials + GRU + LN + MLP
__global__ __launch_bounds__(128)
void k5_gru(const float* __restrict__ Upart, const float* __restrict__ Spart,
            const float* __restrict__ slots_prev,
            const float* __restrict__ wih, const float* __restrict__ whh,
            const float* __restrict__ bih, const float* __restrict__ bhh,
            const float* __restrict__ ln_m_g, const float* __restrict__ ln_m_b,
            const float* __restrict__ w1, const float* __restrict__ b1,
            const float* __restrict__ w2, const float* __restrict__ b2,
            float* __restrict__ out) {
    __shared__ float upd[128];
    __shared__ float sp[128];
    __shared__ float mrow[128];
    __shared__ float hrow[256];
    __shared__ float red[4];
    int t = threadIdx.x;
    int bb = blockIdx.x / 11, s = blockIdx.x % 11;
    float ua = 0.f, sa = 0.f;
    #pragma unroll
    for (int pI = 0; pI < 16; ++pI) {
        ua += Upart[(((size_t)bb * 16 + pI) * 11 + s) * 128 + t];
        sa += Spart[((size_t)bb * 16 + pI) * 11 + s];
    }
    float u = ua / sa;
    upd[t] = u;
    float spv = slots_prev[((size_t)bb * 11 + s) * 128 + t];
    sp[t] = spv;
    __syncthreads();
    float gi[3], gh[3];
    #pragma unroll
    for (int kI = 0; kI < 3; ++kI) {
        int e = t + kI * 128;
        const floatx4* wi = (const floatx4*)(wih + (size_t)e * 128);
        const floatx4* wh = (const floatx4*)(whh + (size_t)e * 128);
        const floatx4* up = (const floatx4*)upd;
        const floatx4* spp = (const floatx4*)sp;
        float a1 = 0.f, a2 = 0.f;
        for (int j = 0; j < 32; ++j) {
            floatx4 wv = wi[j], uv = up[j];
            a1 += wv[0]*uv[0] + wv[1]*uv[1] + wv[2]*uv[2] + wv[3]*uv[3];
            floatx4 w2v = wh[j], sv = spp[j];
            a2 += w2v[0]*sv[0] + w2v[1]*sv[1] + w2v[2]*sv[2] + w2v[3]*sv[3];
        }
        gi[kI] = a1 + bih[e];
        gh[kI] = a2 + bhh[e];
    }
    float r = 1.f / (1.f + __expf(-(gi[0] + gh[0])));
    float z = 1.f / (1.f + __expf(-(gi[1] + gh[1])));
    float nn = tanhf(gi[2] + r * gh[2]);
    float ns = (1.f - z) * nn + z * spv;
    float s1 = ns, s2 = ns * ns;
    #pragma unroll
    for (int off = 32; off > 0; off >>= 1) { s1 += __shfl_xor(s1, off); s2 += __shfl_xor(s2, off); }
    if ((t & 63) == 0) { red[(t >> 6) * 2] = s1; red[(t >> 6) * 2 + 1] = s2; }
    __syncthreads();
    float tot1 = red[0] + red[2], tot2 = red[1] + red[3];
    float mean = tot1 * (1.f / 128.f), var = tot2 * (1.f / 128.f) - mean * mean;
    float rs = rsqrtf(var + 1e-5f);
    mrow[t] = (ns - mean) * rs * ln_m_g[t] + ln_m_b[t];
    __syncthreads();
    #pragma unroll
    for (int kI = 0; kI < 2; ++kI) {
        int k = t + kI * 128;
        const floatx4* wv = (const floatx4*)(w1 + (size_t)k * 128);
        const floatx4* mp = (const floatx4*)mrow;
        float a = 0.f;
        for (int j = 0; j < 32; ++j) {
            floatx4 w_ = wv[j], m_ = mp[j];
            a += w_[0]*m_[0] + w_[1]*m_[1] + w_[2]*m_[2] + w_[3]*m_[3];
        }
        a += b1[k];
        hrow[k] = a > 0.f ? a : 0.f;
    }
    __syncthreads();
    {
        const floatx4* wv = (const floatx4*)(w2 + (size_t)t * 256);
        const floatx4* hp = (const floatx4*)hrow;
        float a = 0.f;
        for (int j = 0; j < 64; ++j) {
            floatx4 w_ = wv[j], h_ = hp[j];
            a += w_[0]*h_[0] + w_[1]*h_[1] + w_[2]*h_[2] + w_[3]*h_[3];
        }
        out[((size_t)bb * 11 + s) * 128 + t] = ns + a + b2[t];
    }
}

// ---------------------------------------------------------------- host
extern "C" void kernel_launch(void* const* d_in, const int* in_sizes, int n_in,
                              void* d_out, int out_size, void* d_ws, size_t ws_size,
                              hipStream_t stream) {
    const float* inputs   = (const float*)d_in[0];
    const float* islots   = (const float*)d_in[1];
    const int*   ip       = (const int*)d_in[2];
    const float* ln_in_g  = (const float*)d_in[3];
    const float* ln_in_b  = (const float*)d_in[4];
    const float* ln_s_g   = (const float*)d_in[5];
    const float* ln_s_b   = (const float*)d_in[6];
    const float* ln_m_g   = (const float*)d_in[7];
    const float* ln_m_b   = (const float*)d_in[8];
    const float* mha_in_w = (const float*)d_in[9];
    const float* mha_in_b = (const float*)d_in[10];
    const float* mha_out_w= (const float*)d_in[11];
    const float* mha_out_b= (const float*)d_in[12];
    const float* attn_w1  = (const float*)d_in[13];
    const float* attn_b1  = (const float*)d_in[14];
    const float* attn_w2  = (const float*)d_in[15];
    const float* attn_b2  = (const float*)d_in[16];
    const float* Wq       = (const float*)d_in[17];
    const float* Wk       = (const float*)d_in[18];
    const float* Wv       = (const float*)d_in[19];
    const float* gru_wih  = (const float*)d_in[20];
    const float* gru_whh  = (const float*)d_in[21];
    const float* gru_bih  = (const float*)d_in[22];
    const float* gru_bhh  = (const float*)d_in[23];
    const float* mlp_w1   = (const float*)d_in[24];
    const float* mlp_b1   = (const float*)d_in[25];
    const float* mlp_w2   = (const float*)d_in[26];
    const float* mlp_b2   = (const float*)d_in[27];
    float* out = (float*)d_out;

    char* ws = (char*)d_ws;
    size_t off = 0;
    auto alloc = [&](size_t bytes) -> void* {
        void* p = ws + off;
        off += (bytes + 255) & ~(size_t)255;
        return p;
    };
    unsigned short* Wkv   = (unsigned short*)alloc((size_t)256 * 192 * 2);
    float* bias_kv        = (float*)alloc(256 * 4);
    float* Wq_s           = (float*)alloc(128 * 128 * 4);
    float* bias_q         = (float*)alloc(128 * 4);
    unsigned short* k1    = (unsigned short*)alloc((size_t)64 * 4096 * 128 * 2);
    unsigned short* v1T   = (unsigned short*)alloc((size_t)64 * 128 * 4096 * 2);
    float* slotsA         = (float*)alloc((size_t)64 * 11 * 128 * 4);
    float* slotsB         = (float*)alloc((size_t)64 * 11 * 128 * 4);
    float* qbuf           = (float*)alloc((size_t)64 * 11 * 128 * 4);
    float* Upart          = (float*)alloc((size_t)64 * 16 * 11 * 128 * 4);
    float* Spart          = (float*)alloc((size_t)64 * 16 * 11 * 4);
    (void)ws_size; (void)in_sizes; (void)n_in; (void)out_size;

    k0_prep<<<384, 64, 0, stream>>>(Wk, Wv, ln_in_g, ln_in_b, Wq, ln_s_g, ln_s_b,
                                    Wkv, bias_kv, Wq_s, bias_q);
    k1_lnproj<<<4096, 256, 0, stream>>>(inputs, Wkv, bias_kv, k1, v1T);
    k2_init<<<64, 256, 0, stream>>>(islots, ip, ln_s_g, ln_s_b, mha_in_w, mha_in_b,
                                    mha_out_w, mha_out_b, attn_w1, attn_b1, attn_w2, attn_b2,
                                    slotsA);
    const float* sprev = slotsA;
    for (int it = 0; it < 2; ++it) {
        k3_q<<<704, 128, 0, stream>>>(sprev, Wq_s, bias_q, qbuf);
        k4_attn<<<1024, 256, 0, stream>>>(k1, v1T, qbuf, Upart, Spart);
        float* dst = (it == 1) ? out : slotsB;
        k5_gru<<<704, 128, 0, stream>>>(Upart, Spart, sprev, gru_wih, gru_whh, gru_bih, gru_bhh,
                                        ln_m_g, ln_m_b, mlp_w1, mlp_b1, mlp_w2, mlp_b2, dst);
        sprev = dst;
    }
}